// Round 2
// 560.274 us; speedup vs baseline: 1.0180x; 1.0180x over previous
//
#include <hip/hip_runtime.h>
#include <hip/hip_bf16.h>
#include <math.h>

// Problem constants: B=32, J=512, E=512, H=8, HD=64
#define Jdim 512
#define Edim 512

typedef short short8 __attribute__((ext_vector_type(8)));
typedef float f32x4 __attribute__((ext_vector_type(4)));
typedef unsigned short u16;
typedef unsigned int u32;

__device__ __forceinline__ u16 f2b(float f) {
    union { float f; u32 u; } v; v.f = f;
    u32 r = (v.u + 0x7FFFu + ((v.u >> 16) & 1u)) >> 16;
    return (u16)r;
}
__device__ __forceinline__ float b2f(u16 u) {
    union { u32 u; float f; } v; v.u = ((u32)u) << 16;
    return v.f;
}

__device__ __forceinline__ void gl_lds16(const void* g, void* l) {
    __builtin_amdgcn_global_load_lds(
        (const __attribute__((address_space(1))) u32*)g,
        (__attribute__((address_space(3))) u32*)l, 16, 0, 0);
}

// ---------------- weight conversion ----------------
__global__ __launch_bounds__(256) void convw(
    const float* __restrict__ Wqkv, const float* __restrict__ Wvp,
    const float* __restrict__ Wproj,
    u16* __restrict__ Wq, u16* __restrict__ Wv, u16* __restrict__ Wp,
    u16* __restrict__ Wcat)
{
    int i = blockIdx.x * 256 + threadIdx.x;      // up to 524288
    if (i < 262144) {
        Wq[i] = f2b(Wqkv[i]);                    // rows 0..511 of W_qkv
        Wv[i] = f2b(Wqkv[524288 + i]);           // rows 1024..1535
        Wp[i] = f2b(Wproj[i]);
    }
    // Wcat: row n (512), col c (1024): [W_qkv rows 512..1023 | W_vproj]
    int n = i >> 10, c = i & 1023;
    float v = (c < 512) ? Wqkv[(size_t)(512 + n) * 512 + c]
                        : Wvp[(size_t)n * 512 + (c - 512)];
    Wcat[i] = f2b(v);
}

// ---------------- x_tan + A_cat ----------------
__global__ __launch_bounds__(256) void xtan_kernel(
    const float* __restrict__ x, const float* __restrict__ xvel,
    float* __restrict__ xtan_out, u16* __restrict__ Acat)
{
    int row = blockIdx.x, tid = threadIdx.x;
    int lane = tid & 63, w = tid >> 6;
    const float* xr = x + (size_t)row * 513;
    float a0 = xr[1 + tid], a1 = xr[1 + tid + 256];
    float ss = a0 * a0 + a1 * a1;
    for (int o = 32; o >= 1; o >>= 1) ss += __shfl_down(ss, o);
    __shared__ float wsum[4];
    if (lane == 0) wsum[w] = ss;
    __syncthreads();
    float nrm = sqrtf(wsum[0] + wsum[1] + wsum[2] + wsum[3]);
    float x0 = fmaxf(xr[0], 1.0f + 1e-7f);
    float theta = acoshf(x0);
    float scl = theta / fmaxf(nrm, 1e-7f);
    float t0 = a0 * scl, t1 = a1 * scl;
    xtan_out[(size_t)row * 512 + tid] = t0;
    xtan_out[(size_t)row * 512 + tid + 256] = t1;
    u16* ac = Acat + (size_t)row * 1024;
    ac[tid] = f2b(t0);
    ac[tid + 256] = f2b(t1);
    const float* vr = xvel + (size_t)row * 513;
    ac[512 + tid] = f2b(vr[1 + tid]);
    ac[768 + tid] = f2b(vr[1 + tid + 256]);
}

// ---------------- fused QKV GEMM: one launch, seg-dispatched B ----------
// grid (12, 128): x = 1536 output cols / 128; seg 0=q (K=512), 1=k (K=1024),
// 2=v (K=512). Same 128x128 tile / 4-wave / XOR-8 swizzle structure.
__global__ __launch_bounds__(256) void gemm_qkv(
    const u16* __restrict__ A,
    const u16* __restrict__ Wq, const u16* __restrict__ Wcat,
    const u16* __restrict__ Wv,
    u16* __restrict__ qbuf, u16* __restrict__ kbuf, u16* __restrict__ vbuf)
{
    __shared__ u16 As[128 * 64];
    __shared__ u16 Bs[128 * 64];
    const int tid = threadIdx.x;
    const int w = tid >> 6, lane = tid & 63, l15 = lane & 15, quad = lane >> 4;
    const int m0 = blockIdx.y * 128;
    const int n0g = blockIdx.x * 128;
    const int seg = n0g >> 9;
    const int n0 = n0g & 511;
    const u16* Bm; int ldb, K; u16* outb;
    if (seg == 0)      { Bm = Wq;   ldb = 512;  K = 512;  outb = qbuf; }
    else if (seg == 1) { Bm = Wcat; ldb = 1024; K = 1024; outb = kbuf; }
    else               { Bm = Wv;   ldb = 512;  K = 512;  outb = vbuf; }
    const int wm = (w & 1) * 64, wn = (w >> 1) * 64;

    f32x4 acc[4][4];
#pragma unroll
    for (int i = 0; i < 4; i++)
#pragma unroll
        for (int j = 0; j < 4; j++) acc[i][j] = (f32x4)0.0f;

    for (int kt = 0; kt < K; kt += 64) {
#pragma unroll
        for (int i = 0; i < 4; i++) {
            int c = i * 256 + tid;
            int row = c >> 3, s = c & 7, gc = s ^ (row & 7);
            gl_lds16(&A[(size_t)(m0 + row) * 1024 + kt + gc * 8],
                     &As[(size_t)(i * 256 + (tid & ~63)) * 8]);
        }
#pragma unroll
        for (int i = 0; i < 4; i++) {
            int c = i * 256 + tid;
            int row = c >> 3, s = c & 7, gc = s ^ (row & 7);
            gl_lds16(&Bm[(size_t)(n0 + row) * ldb + kt + gc * 8],
                     &Bs[(size_t)(i * 256 + (tid & ~63)) * 8]);
        }
        __syncthreads();
#pragma unroll
        for (int kc = 0; kc < 2; kc++) {
            short8 af[4], bf[4];
#pragma unroll
            for (int t = 0; t < 4; t++) {
                int row = wm + t * 16 + l15;
                int slot = (kc * 4 + quad) ^ (row & 7);
                af[t] = *(const short8*)&As[row * 64 + slot * 8];
            }
#pragma unroll
            for (int t = 0; t < 4; t++) {
                int row = wn + t * 16 + l15;
                int slot = (kc * 4 + quad) ^ (row & 7);
                bf[t] = *(const short8*)&Bs[row * 64 + slot * 8];
            }
#pragma unroll
            for (int ti = 0; ti < 4; ti++)
#pragma unroll
                for (int tj = 0; tj < 4; tj++)
                    acc[ti][tj] = __builtin_amdgcn_mfma_f32_16x16x32_bf16(
                        af[ti], bf[tj], acc[ti][tj], 0, 0, 0);
        }
        __syncthreads();
    }

#pragma unroll
    for (int ti = 0; ti < 4; ti++)
#pragma unroll
        for (int tj = 0; tj < 4; tj++)
#pragma unroll
            for (int r = 0; r < 4; r++) {
                int gm = m0 + wm + ti * 16 + quad * 4 + r;   // row (A's m)
                int gn = n0 + wn + tj * 16 + l15;            // col (B's n)
                int b = gm >> 9, j = gm & 511, h = gn >> 6, d = gn & 63;
                outb[(((size_t)(b * 8 + h) * 512 + j) << 6) + d] = f2b(acc[ti][tj][r]);
            }
}

// ---------------- bf16 MFMA GEMM: C = A(MxK) * B(NxK)^T, fp32+bias out ----
__global__ __launch_bounds__(256) void gemm_proj(
    const u16* __restrict__ A, int lda,
    const u16* __restrict__ Bm, int ldb, int K,
    float* __restrict__ out_f, const float* __restrict__ bias)
{
    __shared__ u16 As[128 * 64];
    __shared__ u16 Bs[128 * 64];
    const int tid = threadIdx.x;
    const int w = tid >> 6, lane = tid & 63, l15 = lane & 15, quad = lane >> 4;
    const int m0 = blockIdx.y * 128, n0 = blockIdx.x * 128;
    const int wm = (w & 1) * 64, wn = (w >> 1) * 64;

    f32x4 acc[4][4];
#pragma unroll
    for (int i = 0; i < 4; i++)
#pragma unroll
        for (int j = 0; j < 4; j++) acc[i][j] = (f32x4)0.0f;

    for (int kt = 0; kt < K; kt += 64) {
#pragma unroll
        for (int i = 0; i < 4; i++) {
            int c = i * 256 + tid;
            int row = c >> 3, s = c & 7, gc = s ^ (row & 7);
            gl_lds16(&A[(size_t)(m0 + row) * lda + kt + gc * 8],
                     &As[(size_t)(i * 256 + (tid & ~63)) * 8]);
        }
#pragma unroll
        for (int i = 0; i < 4; i++) {
            int c = i * 256 + tid;
            int row = c >> 3, s = c & 7, gc = s ^ (row & 7);
            gl_lds16(&Bm[(size_t)(n0 + row) * ldb + kt + gc * 8],
                     &Bs[(size_t)(i * 256 + (tid & ~63)) * 8]);
        }
        __syncthreads();
#pragma unroll
        for (int kc = 0; kc < 2; kc++) {
            short8 af[4], bf[4];
#pragma unroll
            for (int t = 0; t < 4; t++) {
                int row = wm + t * 16 + l15;
                int slot = (kc * 4 + quad) ^ (row & 7);
                af[t] = *(const short8*)&As[row * 64 + slot * 8];
            }
#pragma unroll
            for (int t = 0; t < 4; t++) {
                int row = wn + t * 16 + l15;
                int slot = (kc * 4 + quad) ^ (row & 7);
                bf[t] = *(const short8*)&Bs[row * 64 + slot * 8];
            }
#pragma unroll
            for (int ti = 0; ti < 4; ti++)
#pragma unroll
                for (int tj = 0; tj < 4; tj++)
                    acc[ti][tj] = __builtin_amdgcn_mfma_f32_16x16x32_bf16(
                        af[ti], bf[tj], acc[ti][tj], 0, 0, 0);
        }
        __syncthreads();
    }

#pragma unroll
    for (int ti = 0; ti < 4; ti++)
#pragma unroll
        for (int tj = 0; tj < 4; tj++)
#pragma unroll
            for (int r = 0; r < 4; r++) {
                int gm = m0 + wm + ti * 16 + quad * 4 + r;
                int gn = n0 + wn + tj * 16 + l15;
                out_f[(size_t)gm * 512 + gn] = acc[ti][tj][r] + bias[gn];
            }
}

// ---------------- v transpose: [bh][j][d] -> [bh][d][j] ----------------
__global__ __launch_bounds__(256) void vtrans(
    const u16* __restrict__ vb, u16* __restrict__ vT)
{
    __shared__ u16 tile[64][65];
    int bh = blockIdx.x >> 3, jt = blockIdx.x & 7;
    const u16* src = vb + (size_t)bh * 512 * 64 + (size_t)jt * 64 * 64;
#pragma unroll
    for (int i = 0; i < 16; i++) {
        int e = i * 256 + threadIdx.x;
        tile[e >> 6][e & 63] = src[e];
    }
    __syncthreads();
    u16* dst = vT + (size_t)bh * 64 * 512 + jt * 64;
#pragma unroll
    for (int i = 0; i < 16; i++) {
        int e = i * 256 + threadIdx.x;
        int d = e >> 6, jj = e & 63;
        dst[(size_t)d * 512 + jj] = tile[jj][d];
    }
}

// ---------------- fused attention ----------------
// block = one (b,h) + 32-row q tile. 4 waves, wave w covers k in [w*128,(w+1)*128)
__global__ __launch_bounds__(256) void attn_kernel(
    const u16* __restrict__ qb, const u16* __restrict__ kb,
    const u16* __restrict__ vT, const float* __restrict__ bias,
    float* __restrict__ attn_out, u16* __restrict__ z_bf)
{
    __shared__ u16 Sb[32 * 520];
    __shared__ float row_m[32], row_is[32];
    const int tid = threadIdx.x, w = tid >> 6, lane = tid & 63;
    const int l15 = lane & 15, quad = lane >> 4;
    const int bh = blockIdx.x >> 4, qt = blockIdx.x & 15;
    const int q0 = qt * 32;
    const u16* qp = qb + (size_t)bh * 512 * 64;
    const u16* kp = kb + (size_t)bh * 512 * 64;

    // ---- S = q k^T ----
    short8 qf[2][2];
#pragma unroll
    for (int ti = 0; ti < 2; ti++)
#pragma unroll
        for (int kc = 0; kc < 2; kc++)
            qf[ti][kc] = *(const short8*)&qp[(q0 + ti * 16 + l15) * 64 + kc * 32 + quad * 8];

    f32x4 sacc[2][8];
#pragma unroll
    for (int ti = 0; ti < 2; ti++)
#pragma unroll
        for (int kt = 0; kt < 8; kt++) sacc[ti][kt] = (f32x4)0.0f;

    const int kbase = w * 128;
#pragma unroll
    for (int kt = 0; kt < 8; kt++) {
        short8 kf[2];
        int n = kbase + kt * 16 + l15;
#pragma unroll
        for (int kc = 0; kc < 2; kc++)
            kf[kc] = *(const short8*)&kp[n * 64 + kc * 32 + quad * 8];
#pragma unroll
        for (int ti = 0; ti < 2; ti++)
#pragma unroll
            for (int kc = 0; kc < 2; kc++)
                sacc[ti][kt] = __builtin_amdgcn_mfma_f32_16x16x32_bf16(
                    qf[ti][kc], kf[kc], sacc[ti][kt], 0, 0, 0);
    }
    // scale + bias, store S (bf16) to LDS
#pragma unroll
    for (int ti = 0; ti < 2; ti++)
#pragma unroll
        for (int kt = 0; kt < 8; kt++) {
            int col = kbase + kt * 16 + l15;
#pragma unroll
            for (int r = 0; r < 4; r++) {
                int row = ti * 16 + quad * 4 + r;
                float s = sacc[ti][kt][r] * 0.125f +
                          bias[(size_t)(q0 + row) * 512 + col];
                Sb[row * 520 + col] = f2b(s);
            }
        }
    __syncthreads();

    // ---- softmax stats (fp32), vectorized uint2 reads + fast exp ----
    {
        int srow = tid >> 3, li = tid & 7;
        const u16* srp = &Sb[srow * 520];
        float m = -1e30f;
#pragma unroll
        for (int t = 0; t < 16; t++) {
            uint2 sv = *(const uint2*)&srp[(li + 8 * t) * 4];
            float m01 = fmaxf(b2f((u16)(sv.x & 0xffff)), b2f((u16)(sv.x >> 16)));
            float m23 = fmaxf(b2f((u16)(sv.y & 0xffff)), b2f((u16)(sv.y >> 16)));
            m = fmaxf(m, fmaxf(m01, m23));
        }
        m = fmaxf(m, __shfl_xor(m, 1));
        m = fmaxf(m, __shfl_xor(m, 2));
        m = fmaxf(m, __shfl_xor(m, 4));
        if (li == 0) row_m[srow] = m;
        float sum = 0.0f;
#pragma unroll
        for (int t = 0; t < 16; t++) {
            uint2 sv = *(const uint2*)&srp[(li + 8 * t) * 4];
            sum += __expf(b2f((u16)(sv.x & 0xffff)) - m)
                 + __expf(b2f((u16)(sv.x >> 16)) - m)
                 + __expf(b2f((u16)(sv.y & 0xffff)) - m)
                 + __expf(b2f((u16)(sv.y >> 16)) - m);
        }
        sum += __shfl_xor(sum, 1);
        sum += __shfl_xor(sum, 2);
        sum += __shfl_xor(sum, 4);
        if (li == 0) row_is[srow] = 1.0f / sum;
        __syncthreads();
    }

    // ---- P sweep: write attn fp32 to d_out, repack P bf16 in place ----
    float* attn_p = attn_out + (size_t)bh * 512 * 512 + (size_t)q0 * 512;
#pragma unroll
    for (int i = 0; i < 16; i++) {
        int e = i * 256 + tid;
        int row = e >> 7, cq = (e & 127) * 4;
        uint2 sv = *(const uint2*)&Sb[row * 520 + cq];
        float m = row_m[row], is = row_is[row];
        float p0 = __expf(b2f((u16)(sv.x & 0xffff)) - m) * is;
        float p1 = __expf(b2f((u16)(sv.x >> 16)) - m) * is;
        float p2 = __expf(b2f((u16)(sv.y & 0xffff)) - m) * is;
        float p3 = __expf(b2f((u16)(sv.y >> 16)) - m) * is;
        f32x4 pv; pv[0] = p0; pv[1] = p1; pv[2] = p2; pv[3] = p3;
        *(f32x4*)&attn_p[(size_t)row * 512 + cq] = pv;
        uint2 pk;
        pk.x = (u32)f2b(p0) | ((u32)f2b(p1) << 16);
        pk.y = (u32)f2b(p2) | ((u32)f2b(p3) << 16);
        *(uint2*)&Sb[row * 520 + cq] = pk;   // same addresses this thread read
    }
    __syncthreads();

    // ---- z = P @ V ----  wave w owns d-tile [w*16, w*16+16)
    const u16* vp = vT + (size_t)bh * 64 * 512;
    f32x4 zacc[2];
    zacc[0] = (f32x4)0.0f; zacc[1] = (f32x4)0.0f;
    int n0 = w * 16;
#pragma unroll
    for (int kc = 0; kc < 16; kc++) {
        short8 bfv = *(const short8*)&vp[(size_t)(n0 + l15) * 512 + kc * 32 + quad * 8];
#pragma unroll
        for (int ti = 0; ti < 2; ti++) {
            short8 afp = *(const short8*)&Sb[(ti * 16 + l15) * 520 + kc * 32 + quad * 8];
            zacc[ti] = __builtin_amdgcn_mfma_f32_16x16x32_bf16(afp, bfv, zacc[ti], 0, 0, 0);
        }
    }
    int b = bh >> 3, h = bh & 7;
#pragma unroll
    for (int ti = 0; ti < 2; ti++)
#pragma unroll
        for (int r = 0; r < 4; r++) {
            int row = q0 + ti * 16 + quad * 4 + r;
            int d = n0 + l15;
            z_bf[((size_t)b * 512 + row) * 512 + h * 64 + d] = f2b(zacc[ti][r]);
        }
}

// ---------------- exp_map0 ----------------
__global__ __launch_bounds__(256) void expmap_kernel(
    const float* __restrict__ zp, float* __restrict__ out0)
{
    int row = blockIdx.x, tid = threadIdx.x;
    int lane = tid & 63, w = tid >> 6;
    const float* zr = zp + (size_t)row * 512;
    float a0 = zr[tid], a1 = zr[tid + 256];
    float ss = a0 * a0 + a1 * a1;
    for (int o = 32; o >= 1; o >>= 1) ss += __shfl_down(ss, o);
    __shared__ float wsum[4];
    if (lane == 0) wsum[w] = ss;
    __syncthreads();
    float nrm = sqrtf(wsum[0] + wsum[1] + wsum[2] + wsum[3]);
    float scl = sinhf(nrm) / fmaxf(nrm, 1e-7f);
    float* orow = out0 + (size_t)row * 513;
    if (tid == 0) orow[0] = coshf(nrm);
    orow[1 + tid] = a0 * scl;
    orow[1 + tid + 256] = a1 * scl;
}

extern "C" void kernel_launch(void* const* d_in, const int* in_sizes, int n_in,
                              void* d_out, int out_size, void* d_ws, size_t ws_size,
                              hipStream_t stream) {
    const float* x     = (const float*)d_in[0];
    const float* xvel  = (const float*)d_in[1];
    const float* topo  = (const float*)d_in[2];
    const float* Wqkv  = (const float*)d_in[3];
    const float* Wvp   = (const float*)d_in[4];
    const float* Wproj = (const float*)d_in[5];
    const float* bproj = (const float*)d_in[6];

    float* out      = (float*)d_out;
    float* out_zman = out;                  // 32*512*513 = 8,404,992
    float* out_attn = out + 8404992;        // 32*8*512*512 = 67,108,864
    float* out_xtan = out + 75513856;       // 32*512*512 = 8,388,608

    char* ws = (char*)d_ws;
    u16*   Acat  = (u16*)ws;                      // 33,554,432 B
    u16*   Wq    = (u16*)(ws + 33554432);         //    524,288
    u16*   Wv    = (u16*)(ws + 34078720);         //    524,288
    u16*   Wp    = (u16*)(ws + 34603008);         //    524,288
    u16*   Wcat  = (u16*)(ws + 35127296);         //  1,048,576
    u16*   qbuf  = (u16*)(ws + 36175872);         // 16,777,216
    u16*   kbuf  = (u16*)(ws + 52953088);         // 16,777,216
    u16*   vbuf  = (u16*)(ws + 69730304);         // 16,777,216
    u16*   vT    = (u16*)(ws + 86507520);         // 16,777,216
    u16*   zbf   = (u16*)(ws + 103284736);        // 16,777,216
    float* zproj = (float*)(ws + 120061952);      // 33,554,432  (end 153,616,384)

    convw<<<2048, 256, 0, stream>>>(Wqkv, Wvp, Wproj, Wq, Wv, Wp, Wcat);
    xtan_kernel<<<16384, 256, 0, stream>>>(x, xvel, out_xtan, Acat);

    dim3 gq(12, 128);  // 1536 col-tiles x 128 row-tiles, seg-dispatched
    gemm_qkv<<<gq, 256, 0, stream>>>(Acat, Wq, Wcat, Wv, qbuf, kbuf, vbuf);

    vtrans<<<2048, 256, 0, stream>>>(vbuf, vT);

    attn_kernel<<<4096, 256, 0, stream>>>(qbuf, kbuf, vT, topo, out_attn, zbf);

    dim3 g(4, 128);
    gemm_proj<<<g, 256, 0, stream>>>(zbf, 512, Wp, 512, 512, zproj, bproj);
    expmap_kernel<<<16384, 256, 0, stream>>>(zproj, out_zman);
}